// Round 2
// baseline (124.008 us; speedup 1.0000x reference)
//
#include <hip/hip_runtime.h>
#include <stdint.h>

// ElementReadoutMLP: species-routed 2-layer MLP, fused.
// Deterministic pipeline (no atomics, no memset):
//   bhist_k   : per-256-atom-block species histogram via ballots
//   scan_k    : chunked deterministic scan -> absolute block offsets,
//               species starts, tile offsets
//   dscatter_k: ballot-rank scatter -> sorted atom indices (bit-deterministic)
//   convw_k   : W1 [e][k][n] fp32 -> wt [e][n][k] bf16
//   gemm_k    : grouped bf16-MFMA GEMM (64 atoms x 256 out per block,
//               single species per tile) + fused bias+SiLU+W2-dot epilogue

#define NDIM 256
#define CHUNKS 16   // scan chunks per species (NE*CHUNKS <= 256)

typedef __attribute__((ext_vector_type(8))) short short8;
typedef __attribute__((ext_vector_type(8))) unsigned short ushort8;
typedef __attribute__((ext_vector_type(4))) float f32x4;

__device__ __forceinline__ unsigned short f2bf(float f) {
  unsigned u = __float_as_uint(f);
  u = (u + 0x7FFFu + ((u >> 16) & 1u)) >> 16;   // round-to-nearest-even
  return (unsigned short)u;
}

// ---- prep kernels -----------------------------------------------------------

__global__ void convw_k(const float* __restrict__ W1, unsigned short* __restrict__ wt, int NE) {
  int g = blockIdx.x * 256 + threadIdx.x;
  if (g >= NE * 65536) return;
  int e = g >> 16, rem = g & 65535, n = rem >> 8, k = rem & 255;
  wt[g] = f2bf(W1[((size_t)e << 16) + ((size_t)k << 8) + n]);
}

// per-block histogram, deterministic (ballot-based, no atomics)
__global__ void bhist_k(const int* __restrict__ sp, int n, int* __restrict__ bc, int NE) {
  __shared__ int wc[4][16];
  int tid = threadIdx.x;
  int i = blockIdx.x * 256 + tid;
  int s = (i < n) ? sp[i] : -1;
  int w = tid >> 6, lane = tid & 63;
  for (int e = 0; e < NE; ++e) {
    unsigned long long m = __ballot(s == e);
    if (lane == 0) wc[w][e] = __popcll(m);
  }
  __syncthreads();
  if (tid < NE) bc[blockIdx.x * NE + tid] = wc[0][tid] + wc[1][tid] + wc[2][tid] + wc[3][tid];
}

// deterministic scan: blockCounts -> absolute blockOffs, atom_start, tile_off
__global__ void scan_k(const int* __restrict__ bc, int* __restrict__ bo,
                       int* __restrict__ atom_start, int* __restrict__ tile_off,
                       int nblocks, int NE) {
  __shared__ int csum[256];   // [e*CHUNKS + c] chunk sums
  __shared__ int coff[256];   // [e*CHUNKS + c] chunk exclusive offsets (within species)
  __shared__ int stot[16];    // species totals
  __shared__ int sbase[16];   // species atom base
  int tid = threadIdx.x;
  int per = (nblocks + CHUNKS - 1) / CHUNKS;
  int e = tid / CHUNKS, c = tid % CHUNKS;
  int b0 = c * per, b1 = b0 + per; if (b1 > nblocks) b1 = nblocks;
  if (tid < NE * CHUNKS) {
    int s = 0;
    for (int b = b0; b < b1; ++b) s += bc[b * NE + e];
    csum[tid] = s;
  }
  __syncthreads();
  if (tid < NE) {
    int r = 0;
    for (int c2 = 0; c2 < CHUNKS; ++c2) { coff[tid * CHUNKS + c2] = r; r += csum[tid * CHUNKS + c2]; }
    stot[tid] = r;
  }
  __syncthreads();
  if (tid == 0) {
    int a = 0, t = 0;
    for (int e2 = 0; e2 < NE; ++e2) {
      sbase[e2] = a;
      atom_start[e2] = a; tile_off[e2] = t;
      a += stot[e2]; t += (stot[e2] + 63) >> 6;
    }
    atom_start[NE] = a; tile_off[NE] = t;
  }
  __syncthreads();
  if (tid < NE * CHUNKS) {
    int run = sbase[e] + coff[tid];
    for (int b = b0; b < b1; ++b) { bo[b * NE + e] = run; run += bc[b * NE + e]; }
  }
}

// deterministic scatter: rank = block-offset + wave-prefix + lane-prefix
__global__ void dscatter_k(const int* __restrict__ sp, int n, const int* __restrict__ bo,
                           int* __restrict__ sorted, int NE) {
  __shared__ int wc[4][16];
  int tid = threadIdx.x;
  int i = blockIdx.x * 256 + tid;
  int s = (i < n) ? sp[i] : -1;
  int w = tid >> 6, lane = tid & 63;
  for (int e = 0; e < NE; ++e) {
    unsigned long long m = __ballot(s == e);
    if (lane == 0) wc[w][e] = __popcll(m);
  }
  __syncthreads();
  for (int e = 0; e < NE; ++e) {
    unsigned long long m = __ballot(s == e);
    if (s == e) {
      int wpre = 0;
      for (int w2 = 0; w2 < 4; ++w2) if (w2 < w) wpre += wc[w2][e];
      int rank = __popcll(m & ((1ull << lane) - 1ull));
      sorted[bo[blockIdx.x * NE + e] + wpre + rank] = i;
    }
  }
}

// ---- fused grouped GEMM + SiLU + layer2 ------------------------------------

__global__ __launch_bounds__(256) void gemm_k(
    const float* __restrict__ x, const unsigned short* __restrict__ wt,
    const float* __restrict__ b1, const float* __restrict__ w2,
    const float* __restrict__ b2, const int* __restrict__ sorted,
    const int* __restrict__ atom_start, const int* __restrict__ tile_off,
    float* __restrict__ out, int NE)
{
  // LDS: A tile 64x256 bf16 = 32 KB (swizzled), B chunk 256n x 32k bf16 = 16 KB
  // (swizzled); B region reused for the 1 KB cross-wave partial buffer.
  __shared__ __align__(16) char smem[49152];
  char* ldsA = smem;
  char* ldsB = smem + 32768;
  float* partLds = (float*)(smem + 32768);

  int b = blockIdx.x;
  if (b >= tile_off[NE]) return;
  int e = NE - 1;
  for (int i = 0; i < NE; ++i) { if (b < tile_off[i + 1]) { e = i; break; } }
  int t = b - tile_off[e];
  int rowStart = atom_start[e] + t * 64;
  int rowsValid = atom_start[e + 1] - rowStart;
  if (rowsValid > 64) rowsValid = 64;

  int tid = threadIdx.x;

  // ---- stage A: gather 64 atom rows, fp32 -> bf16, XOR-swizzled LDS ----
  {
    int r = tid >> 2, q = tid & 3;
    int atom = (r < rowsValid) ? sorted[rowStart + r] : -1;
    const float* xrow = x + (size_t)(atom < 0 ? 0 : atom) * NDIM;
    unsigned swz = (unsigned)((r & 7) << 4);
    unsigned rb = (unsigned)(r * 512);
    #pragma unroll
    for (int i = 0; i < 16; ++i) {
      int k = q * 64 + i * 4;
      float4 v = make_float4(0.f, 0.f, 0.f, 0.f);
      if (atom >= 0) v = *(const float4*)(xrow + k);
      ushort4 h;
      h.x = f2bf(v.x); h.y = f2bf(v.y); h.z = f2bf(v.z); h.w = f2bf(v.w);
      *(ushort4*)(ldsA + ((rb + (unsigned)(k * 2)) ^ swz)) = h;
    }
  }

  int lane = tid & 63, wid = tid >> 6;
  int lr = lane & 15, lg = lane >> 4;

  f32x4 acc[4][4];
  const f32x4 zero = {0.f, 0.f, 0.f, 0.f};
  #pragma unroll
  for (int i = 0; i < 4; ++i)
    #pragma unroll
    for (int j = 0; j < 4; ++j) acc[i][j] = zero;

  const unsigned short* wbase = wt + ((size_t)e << 16);   // Wt[e][n][k]

  for (int step = 0; step < 8; ++step) {
    int k0 = step * 32;
    __syncthreads();   // prior iteration done reading ldsB (and A stage visible)
    {
      // stage B chunk: thread n loads Wt[e][n][k0..k0+32), 4x16B, swizzled
      int n = tid;
      const unsigned short* wrow = wbase + (size_t)n * 256 + k0;
      unsigned nb = (unsigned)(n * 64);
      unsigned swz = (unsigned)((n & 7) << 4);
      #pragma unroll
      for (int i = 0; i < 4; ++i) {
        ushort8 v = *(const ushort8*)(wrow + i * 8);
        *(ushort8*)(ldsB + ((nb + (unsigned)(i * 16)) ^ swz)) = v;
      }
    }
    __syncthreads();

    short8 af[4], bf[4];
    #pragma unroll
    for (int mf = 0; mf < 4; ++mf) {
      int r = mf * 16 + lr;
      unsigned off = ((unsigned)(r * 512 + (k0 + lg * 8) * 2)) ^ ((unsigned)((r & 7) << 4));
      af[mf] = *(const short8*)(ldsA + off);
    }
    #pragma unroll
    for (int nf = 0; nf < 4; ++nf) {
      int n = wid * 64 + nf * 16 + lr;
      unsigned off = ((unsigned)(n * 64 + lg * 16)) ^ ((unsigned)((n & 7) << 4));
      bf[nf] = *(const short8*)(ldsB + off);
    }
    #pragma unroll
    for (int mf = 0; mf < 4; ++mf)
      #pragma unroll
      for (int nf = 0; nf < 4; ++nf)
        acc[mf][nf] = __builtin_amdgcn_mfma_f32_16x16x32_bf16(af[mf], bf[nf], acc[mf][nf], 0, 0, 0);
  }

  // ---- epilogue: +b1, SiLU, dot with W2, reduce ----
  // C/D layout: col = lane&15 (+nf*16 + wid*64), row = (lane>>4)*4 + reg (+mf*16)
  const float* b1p = b1 + (size_t)e * NDIM;
  const float* w2p = w2 + (size_t)e * NDIM;
  float psum[4][4];   // [mf][reg] partial over this lane's 4 columns
  #pragma unroll
  for (int mf = 0; mf < 4; ++mf)
    #pragma unroll
    for (int rg = 0; rg < 4; ++rg) psum[mf][rg] = 0.f;

  #pragma unroll
  for (int nf = 0; nf < 4; ++nf) {
    int ncol = wid * 64 + nf * 16 + lr;
    float bb = b1p[ncol];
    float wv = w2p[ncol];
    #pragma unroll
    for (int mf = 0; mf < 4; ++mf)
      #pragma unroll
      for (int rg = 0; rg < 4; ++rg) {
        float h = acc[mf][nf][rg] + bb;
        float sv = h / (1.f + __expf(-h));   // SiLU
        psum[mf][rg] += sv * wv;
      }
  }

  // reduce over the 16 lanes sharing lg (sums this wave's 64 columns)
  #pragma unroll
  for (int mf = 0; mf < 4; ++mf)
    #pragma unroll
    for (int rg = 0; rg < 4; ++rg) {
      float v = psum[mf][rg];
      v += __shfl_xor(v, 1, 64);
      v += __shfl_xor(v, 2, 64);
      v += __shfl_xor(v, 4, 64);
      v += __shfl_xor(v, 8, 64);
      psum[mf][rg] = v;
    }

  __syncthreads();   // everyone done reading ldsB -> safe to reuse as partLds
  if (lr == 0) {
    #pragma unroll
    for (int mf = 0; mf < 4; ++mf)
      #pragma unroll
      for (int rg = 0; rg < 4; ++rg)
        partLds[wid * 64 + mf * 16 + lg * 4 + rg] = psum[mf][rg];
  }
  __syncthreads();
  if (tid < 64 && tid < rowsValid) {
    float s = partLds[tid] + partLds[64 + tid] + partLds[128 + tid] + partLds[192 + tid]
            + b2[e];
    out[sorted[rowStart + tid]] = s;
  }
}

// ---- launch -----------------------------------------------------------------

extern "C" void kernel_launch(void* const* d_in, const int* in_sizes, int n_in,
                              void* d_out, int out_size, void* d_ws, size_t ws_size,
                              hipStream_t stream) {
  const float* x  = (const float*)d_in[0];
  const int*   sp = (const int*)d_in[1];
  const float* W1 = (const float*)d_in[2];
  const float* b1 = (const float*)d_in[3];
  const float* W2 = (const float*)d_in[4];
  const float* b2 = (const float*)d_in[5];
  float* out = (float*)d_out;

  int n_atoms = in_sizes[0] / NDIM;
  int NE = in_sizes[2] / (NDIM * NDIM);
  int nblocks = (n_atoms + 255) / 256;

  // workspace layout (all 256-aligned); every word read is written this call.
  char* wsb = (char*)d_ws;
  size_t o = 0;
  int* bc = (int*)(wsb + o);         o += ((size_t)nblocks * NE * 4 + 255) & ~(size_t)255;
  int* bo = (int*)(wsb + o);         o += ((size_t)nblocks * NE * 4 + 255) & ~(size_t)255;
  int* atom_start = (int*)(wsb + o); o += 256;
  int* tile_off   = (int*)(wsb + o); o += 256;
  int* sorted     = (int*)(wsb + o); o += ((size_t)n_atoms * 4 + 255) & ~(size_t)255;
  unsigned short* wt = (unsigned short*)(wsb + o);
  // total ~= 1.75 MB for n=100000, NE=10

  hipLaunchKernelGGL(convw_k, dim3((NE * 65536 + 255) / 256), dim3(256), 0, stream,
                     W1, wt, NE);
  hipLaunchKernelGGL(bhist_k, dim3(nblocks), dim3(256), 0, stream, sp, n_atoms, bc, NE);
  hipLaunchKernelGGL(scan_k, dim3(1), dim3(256), 0, stream, bc, bo, atom_start, tile_off,
                     nblocks, NE);
  hipLaunchKernelGGL(dscatter_k, dim3(nblocks), dim3(256), 0, stream, sp, n_atoms, bo,
                     sorted, NE);

  int maxTiles = (n_atoms + 63) / 64 + NE;   // fixed grid; extras exit on tile_off[NE]
  hipLaunchKernelGGL(gemm_k, dim3(maxTiles), dim3(256), 0, stream,
                     x, wt, b1, W2, b2, sorted, atom_start, tile_off, out, NE);
}

// Round 3
// 94.601 us; speedup vs baseline: 1.3109x; 1.3109x over previous
//
#include <hip/hip_runtime.h>
#include <stdint.h>

// ElementReadoutMLP: species-routed 2-layer MLP, fused.
// Deterministic pipeline (no atomics, no memset):
//   bhist_k / scan_k / dscatter_k : countsort atoms by species (ballot-based)
//   convw_k : W1 [e][k][n] fp32 -> wt, PRE-SWIZZLED k-chunked bf16 layout so
//             gemm stages B with linear global_load_lds (rule #21)
//   gemm_k  : grouped bf16-MFMA GEMM (64 atoms x 256 out per block, single
//             species per tile), B double-buffered + stage-ahead, fused
//             bias+SiLU+W2-dot epilogue.

#define NDIM 256
#define CHUNKS 16      // scan chunks per species (NE*CHUNKS <= 256)
#define BCHUNK 16384   // bytes per B k-chunk (256 n x 32 k x 2B)

typedef __attribute__((ext_vector_type(8))) short short8;
typedef __attribute__((ext_vector_type(8))) unsigned short ushort8;
typedef __attribute__((ext_vector_type(4))) float f32x4;

__device__ __forceinline__ unsigned short f2bf(float f) {
  unsigned u = __float_as_uint(f);
  u = (u + 0x7FFFu + ((u >> 16) & 1u)) >> 16;   // round-to-nearest-even
  return (unsigned short)u;
}

// async global->LDS, 16B per lane; lds dest must be wave-uniform base.
__device__ __forceinline__ void gload_lds16(const void* gsrc, void* ldst) {
  __builtin_amdgcn_global_load_lds(
      (const __attribute__((address_space(1))) unsigned*)gsrc,
      (__attribute__((address_space(3))) unsigned*)(uintptr_t)(unsigned)(uintptr_t)ldst,
      16, 0, 0);
}

// ---- prep kernels -----------------------------------------------------------

// wt layout: chunk(e,step) = wt + (e*8+step)*BCHUNK bytes; within chunk,
// bf16 for (n,kk) at byte ((n*64 + kk*2) ^ ((n&7)<<4)).  Linear copy of this
// chunk into LDS reproduces the swizzled layout gemm_k's ds_reads expect.
__global__ void convw_k(const float* __restrict__ W1, unsigned short* __restrict__ wt, int NE) {
  int t = blockIdx.x * 256 + threadIdx.x;          // ((e*8+step)*4 + g)*256 + n
  if (t >= NE * 8192) return;
  int n = t & 255;
  int g = (t >> 8) & 3;            // kk-group of 8
  int step = (t >> 10) & 7;
  int e = t >> 13;
  int k0 = step * 32 + g * 8;
  const float* src = W1 + ((size_t)e << 16) + (size_t)k0 * NDIM + n;  // stride NDIM over j
  unsigned short v[8];
  #pragma unroll
  for (int j = 0; j < 8; ++j) v[j] = f2bf(src[j * NDIM]);
  char* chunk = (char*)wt + (size_t)(e * 8 + step) * BCHUNK;
  unsigned off = ((unsigned)(n * 64 + g * 16)) ^ ((unsigned)((n & 7) << 4));
  *(ushort8*)(chunk + off) = *(ushort8*)v;
}

// per-block histogram, deterministic (ballot-based, no atomics)
__global__ void bhist_k(const int* __restrict__ sp, int n, int* __restrict__ bc, int NE) {
  __shared__ int wc[4][16];
  int tid = threadIdx.x;
  int i = blockIdx.x * 256 + tid;
  int s = (i < n) ? sp[i] : -1;
  int w = tid >> 6, lane = tid & 63;
  for (int e = 0; e < NE; ++e) {
    unsigned long long m = __ballot(s == e);
    if (lane == 0) wc[w][e] = __popcll(m);
  }
  __syncthreads();
  if (tid < NE) bc[blockIdx.x * NE + tid] = wc[0][tid] + wc[1][tid] + wc[2][tid] + wc[3][tid];
}

// deterministic scan: blockCounts -> absolute blockOffs, atom_start, tile_off
__global__ void scan_k(const int* __restrict__ bc, int* __restrict__ bo,
                       int* __restrict__ atom_start, int* __restrict__ tile_off,
                       int nblocks, int NE) {
  __shared__ int csum[256];
  __shared__ int coff[256];
  __shared__ int stot[16];
  __shared__ int sbase[16];
  int tid = threadIdx.x;
  int per = (nblocks + CHUNKS - 1) / CHUNKS;
  int e = tid / CHUNKS, c = tid % CHUNKS;
  int b0 = c * per, b1 = b0 + per; if (b1 > nblocks) b1 = nblocks;
  if (tid < NE * CHUNKS) {
    int s = 0;
    for (int b = b0; b < b1; ++b) s += bc[b * NE + e];
    csum[tid] = s;
  }
  __syncthreads();
  if (tid < NE) {
    int r = 0;
    for (int c2 = 0; c2 < CHUNKS; ++c2) { coff[tid * CHUNKS + c2] = r; r += csum[tid * CHUNKS + c2]; }
    stot[tid] = r;
  }
  __syncthreads();
  if (tid == 0) {
    int a = 0, t = 0;
    for (int e2 = 0; e2 < NE; ++e2) {
      sbase[e2] = a;
      atom_start[e2] = a; tile_off[e2] = t;
      a += stot[e2]; t += (stot[e2] + 63) >> 6;
    }
    atom_start[NE] = a; tile_off[NE] = t;
  }
  __syncthreads();
  if (tid < NE * CHUNKS) {
    int run = sbase[e] + coff[tid];
    for (int b = b0; b < b1; ++b) { bo[b * NE + e] = run; run += bc[b * NE + e]; }
  }
}

// deterministic scatter: rank = block-offset + wave-prefix + lane-prefix
__global__ void dscatter_k(const int* __restrict__ sp, int n, const int* __restrict__ bo,
                           int* __restrict__ sorted, int NE) {
  __shared__ int wc[4][16];
  int tid = threadIdx.x;
  int i = blockIdx.x * 256 + tid;
  int s = (i < n) ? sp[i] : -1;
  int w = tid >> 6, lane = tid & 63;
  for (int e = 0; e < NE; ++e) {
    unsigned long long m = __ballot(s == e);
    if (lane == 0) wc[w][e] = __popcll(m);
  }
  __syncthreads();
  for (int e = 0; e < NE; ++e) {
    unsigned long long m = __ballot(s == e);
    if (s == e) {
      int wpre = 0;
      for (int w2 = 0; w2 < 4; ++w2) if (w2 < w) wpre += wc[w2][e];
      int rank = __popcll(m & ((1ull << lane) - 1ull));
      sorted[bo[blockIdx.x * NE + e] + wpre + rank] = i;
    }
  }
}

// ---- fused grouped GEMM + SiLU + layer2 ------------------------------------

__global__ __launch_bounds__(256) void gemm_k(
    const float* __restrict__ x, const unsigned short* __restrict__ wt,
    const float* __restrict__ b1, const float* __restrict__ w2,
    const float* __restrict__ b2, const int* __restrict__ sorted,
    const int* __restrict__ atom_start, const int* __restrict__ tile_off,
    float* __restrict__ out, int NE)
{
  // LDS: A tile 64x256 bf16 swizzled = 32 KB; B double buffer 2 x 16 KB.
  // B half 0 reused as the 1 KB cross-wave partial buffer in the epilogue.
  __shared__ __align__(16) char smem[65536];
  char* ldsA = smem;
  char* ldsB[2] = { smem + 32768, smem + 49152 };
  float* partLds = (float*)(smem + 32768);

  int b = blockIdx.x;
  if (b >= tile_off[NE]) return;
  int e = NE - 1;
  for (int i = 0; i < NE; ++i) { if (b < tile_off[i + 1]) { e = i; break; } }
  int t = b - tile_off[e];
  int rowStart = atom_start[e] + t * 64;
  int rowsValid = atom_start[e + 1] - rowStart;
  if (rowsValid > 64) rowsValid = 64;

  int tid = threadIdx.x;
  int lane = tid & 63, wid = tid >> 6;

  const char* wbase = (const char*)wt + (size_t)e * 8 * BCHUNK;

  // ---- prologue: kick off B chunk 0 while staging A ----
  #pragma unroll
  for (int j = 0; j < 4; ++j)
    gload_lds16(wbase + wid * 4096 + j * 1024 + lane * 16,
                ldsB[0] + wid * 4096 + j * 1024);

  // ---- stage A: one wave reads one full 1KB x-row per instruction ----
  {
    #pragma unroll
    for (int i = 0; i < 16; ++i) {
      int r = wid * 16 + i;
      int atom = (r < rowsValid) ? sorted[rowStart + r] : -1;
      ushort4 h = make_ushort4(0, 0, 0, 0);
      if (atom >= 0) {
        float4 v = *(const float4*)(x + (size_t)atom * NDIM + lane * 4);
        h.x = f2bf(v.x); h.y = f2bf(v.y); h.z = f2bf(v.z); h.w = f2bf(v.w);
      }
      unsigned off = ((unsigned)(r * 512 + lane * 8)) ^ ((unsigned)((r & 7) << 4));
      *(ushort4*)(ldsA + off) = h;
    }
  }

  int lr = lane & 15, lg = lane >> 4;

  f32x4 acc[4][4];
  const f32x4 zero = {0.f, 0.f, 0.f, 0.f};
  #pragma unroll
  for (int i = 0; i < 4; ++i)
    #pragma unroll
    for (int j = 0; j < 4; ++j) acc[i][j] = zero;

  __syncthreads();   // drains A ds_writes + B chunk-0 vmcnt

  // ---- K loop: stage-ahead double-buffered B, one barrier per step ----
  for (int step = 0; step < 8; ++step) {
    char* cur = ldsB[step & 1];
    if (step < 7) {
      char* nxt = ldsB[(step + 1) & 1];
      const char* src = wbase + (size_t)(step + 1) * BCHUNK;
      #pragma unroll
      for (int j = 0; j < 4; ++j)
        gload_lds16(src + wid * 4096 + j * 1024 + lane * 16,
                    nxt + wid * 4096 + j * 1024);
    }

    int k0 = step * 32;
    short8 af[4], bf[4];
    #pragma unroll
    for (int mf = 0; mf < 4; ++mf) {
      int r = mf * 16 + lr;
      unsigned off = ((unsigned)(r * 512 + (k0 + lg * 8) * 2)) ^ ((unsigned)((r & 7) << 4));
      af[mf] = *(const short8*)(ldsA + off);
    }
    #pragma unroll
    for (int nf = 0; nf < 4; ++nf) {
      int n = wid * 64 + nf * 16 + lr;
      unsigned off = ((unsigned)(n * 64 + lg * 16)) ^ ((unsigned)((n & 7) << 4));
      bf[nf] = *(const short8*)(cur + off);
    }
    #pragma unroll
    for (int mf = 0; mf < 4; ++mf)
      #pragma unroll
      for (int nf = 0; nf < 4; ++nf)
        acc[mf][nf] = __builtin_amdgcn_mfma_f32_16x16x32_bf16(af[mf], bf[nf], acc[mf][nf], 0, 0, 0);

    __syncthreads();   // drains next-chunk stage; all waves done reading cur
  }

  // ---- epilogue: +b1, SiLU, dot with W2, reduce ----
  // C/D layout: col = lane&15 (+nf*16 + wid*64), row = (lane>>4)*4 + reg (+mf*16)
  const float* b1p = b1 + (size_t)e * NDIM;
  const float* w2p = w2 + (size_t)e * NDIM;
  float psum[4][4];
  #pragma unroll
  for (int mf = 0; mf < 4; ++mf)
    #pragma unroll
    for (int rg = 0; rg < 4; ++rg) psum[mf][rg] = 0.f;

  #pragma unroll
  for (int nf = 0; nf < 4; ++nf) {
    int ncol = wid * 64 + nf * 16 + lr;
    float bb = b1p[ncol];
    float wv = w2p[ncol];
    #pragma unroll
    for (int mf = 0; mf < 4; ++mf)
      #pragma unroll
      for (int rg = 0; rg < 4; ++rg) {
        float h = acc[mf][nf][rg] + bb;
        float sv = h * __builtin_amdgcn_rcpf(1.f + __expf(-h));   // SiLU
        psum[mf][rg] += sv * wv;
      }
  }

  // reduce over the 16 lanes sharing lg (sums this wave's 64 columns)
  #pragma unroll
  for (int mf = 0; mf < 4; ++mf)
    #pragma unroll
    for (int rg = 0; rg < 4; ++rg) {
      float v = psum[mf][rg];
      v += __shfl_xor(v, 1, 64);
      v += __shfl_xor(v, 2, 64);
      v += __shfl_xor(v, 4, 64);
      v += __shfl_xor(v, 8, 64);
      psum[mf][rg] = v;
    }

  __syncthreads();   // safe to reuse ldsB[0] as partLds
  if (lr == 0) {
    #pragma unroll
    for (int mf = 0; mf < 4; ++mf)
      #pragma unroll
      for (int rg = 0; rg < 4; ++rg)
        partLds[wid * 64 + mf * 16 + lg * 4 + rg] = psum[mf][rg];
  }
  __syncthreads();
  if (tid < 64 && tid < rowsValid) {
    float s = partLds[tid] + partLds[64 + tid] + partLds[128 + tid] + partLds[192 + tid]
            + b2[e];
    out[sorted[rowStart + tid]] = s;
  }
}

// ---- launch -----------------------------------------------------------------

extern "C" void kernel_launch(void* const* d_in, const int* in_sizes, int n_in,
                              void* d_out, int out_size, void* d_ws, size_t ws_size,
                              hipStream_t stream) {
  const float* x  = (const float*)d_in[0];
  const int*   sp = (const int*)d_in[1];
  const float* W1 = (const float*)d_in[2];
  const float* b1 = (const float*)d_in[3];
  const float* W2 = (const float*)d_in[4];
  const float* b2 = (const float*)d_in[5];
  float* out = (float*)d_out;

  int n_atoms = in_sizes[0] / NDIM;
  int NE = in_sizes[2] / (NDIM * NDIM);
  int nblocks = (n_atoms + 255) / 256;

  // workspace layout (all 256-aligned); every word read is written this call.
  char* wsb = (char*)d_ws;
  size_t o = 0;
  int* bc = (int*)(wsb + o);         o += ((size_t)nblocks * NE * 4 + 255) & ~(size_t)255;
  int* bo = (int*)(wsb + o);         o += ((size_t)nblocks * NE * 4 + 255) & ~(size_t)255;
  int* atom_start = (int*)(wsb + o); o += 256;
  int* tile_off   = (int*)(wsb + o); o += 256;
  int* sorted     = (int*)(wsb + o); o += ((size_t)n_atoms * 4 + 255) & ~(size_t)255;
  unsigned short* wt = (unsigned short*)(wsb + o);   // NE*128KB, 256-aligned

  hipLaunchKernelGGL(convw_k, dim3((NE * 8192 + 255) / 256), dim3(256), 0, stream,
                     W1, wt, NE);
  hipLaunchKernelGGL(bhist_k, dim3(nblocks), dim3(256), 0, stream, sp, n_atoms, bc, NE);
  hipLaunchKernelGGL(scan_k, dim3(1), dim3(256), 0, stream, bc, bo, atom_start, tile_off,
                     nblocks, NE);
  hipLaunchKernelGGL(dscatter_k, dim3(nblocks), dim3(256), 0, stream, sp, n_atoms, bo,
                     sorted, NE);

  int maxTiles = (n_atoms + 63) / 64 + NE;   // fixed grid; extras exit on tile_off[NE]
  hipLaunchKernelGGL(gemm_k, dim3(maxTiles), dim3(256), 0, stream,
                     x, wt, b1, W2, b2, sorted, atom_start, tile_off, out, NE);
}

// Round 4
// 74.540 us; speedup vs baseline: 1.6636x; 1.2691x over previous
//
#include <hip/hip_runtime.h>
#include <hip/hip_bf16.h>
#include <stdint.h>

// ElementReadoutMLP: species-routed 2-layer MLP, fused.
// Deterministic pipeline (no atomics, no memset):
//   bhist_k / scan_k / dscatter_k : countsort atoms by species (ballot-based)
//   convw_k : W1 [e][k][n] fp32 -> wt, PRE-SWIZZLED k-chunked bf16 layout so
//             gemm stages B with linear global_load_lds (rule #21)
//   gemm_k  : grouped bf16-MFMA GEMM, 32 atoms x 256 out per block.
//             A staged as fp32 via global_load_lds (full tile async in flight,
//             Little's-law fix), converted to bf16 in-register post-LDS-read.
//             Fused bias+SiLU+W2-dot epilogue.

#define NDIM 256
#define CHUNKS 16      // scan chunks per species (NE*CHUNKS <= 256)
#define BCHUNK 16384   // bytes per B k-chunk (256 n x 32 k x 2B)
#define TROWS 32       // atoms per tile
#define ROWB 1040      // A row pitch bytes (1024 + 16 pad -> 2-way banks, free)

typedef __attribute__((ext_vector_type(8))) short short8;
typedef __attribute__((ext_vector_type(8))) unsigned short ushort8;
typedef __attribute__((ext_vector_type(4))) float f32x4;

__device__ __forceinline__ unsigned short f2bf(float f) {
  unsigned u = __float_as_uint(f);
  u = (u + 0x7FFFu + ((u >> 16) & 1u)) >> 16;   // round-to-nearest-even
  return (unsigned short)u;
}

// async global->LDS, 16B per lane; lds dest must be wave-uniform base.
__device__ __forceinline__ void gload_lds16(const void* gsrc, void* ldst) {
  __builtin_amdgcn_global_load_lds(
      (const __attribute__((address_space(1))) unsigned*)gsrc,
      (__attribute__((address_space(3))) unsigned*)(uintptr_t)(unsigned)(uintptr_t)ldst,
      16, 0, 0);
}

// pack 8 fp32 -> short8 of bf16 (RNE, packed cvt)
__device__ __forceinline__ short8 cvt8(float4 lo, float4 hi) {
  union { short8 s; unsigned u[4]; } r;
  __hip_bfloat162 t;
  t = __float22bfloat162_rn(make_float2(lo.x, lo.y)); r.u[0] = *(unsigned*)&t;
  t = __float22bfloat162_rn(make_float2(lo.z, lo.w)); r.u[1] = *(unsigned*)&t;
  t = __float22bfloat162_rn(make_float2(hi.x, hi.y)); r.u[2] = *(unsigned*)&t;
  t = __float22bfloat162_rn(make_float2(hi.z, hi.w)); r.u[3] = *(unsigned*)&t;
  return r.s;
}

// ---- prep kernels -----------------------------------------------------------

// wt layout: chunk(e,step) = wt + (e*8+step)*BCHUNK bytes; within chunk,
// bf16 for (n,kk) at byte ((n*64 + kk*2) ^ ((n&7)<<4)).  Linear copy of this
// chunk into LDS reproduces the swizzled layout gemm_k's ds_reads expect.
__global__ void convw_k(const float* __restrict__ W1, unsigned short* __restrict__ wt, int NE) {
  int t = blockIdx.x * 256 + threadIdx.x;          // ((e*8+step)*4 + g)*256 + n
  if (t >= NE * 8192) return;
  int n = t & 255;
  int g = (t >> 8) & 3;            // kk-group of 8
  int step = (t >> 10) & 7;
  int e = t >> 13;
  int k0 = step * 32 + g * 8;
  const float* src = W1 + ((size_t)e << 16) + (size_t)k0 * NDIM + n;  // stride NDIM over j
  unsigned short v[8];
  #pragma unroll
  for (int j = 0; j < 8; ++j) v[j] = f2bf(src[j * NDIM]);
  char* chunk = (char*)wt + (size_t)(e * 8 + step) * BCHUNK;
  unsigned off = ((unsigned)(n * 64 + g * 16)) ^ ((unsigned)((n & 7) << 4));
  *(ushort8*)(chunk + off) = *(ushort8*)v;
}

// per-block histogram, deterministic (ballot-based, no atomics)
__global__ void bhist_k(const int* __restrict__ sp, int n, int* __restrict__ bc, int NE) {
  __shared__ int wc[4][16];
  int tid = threadIdx.x;
  int i = blockIdx.x * 256 + tid;
  int s = (i < n) ? sp[i] : -1;
  int w = tid >> 6, lane = tid & 63;
  for (int e = 0; e < NE; ++e) {
    unsigned long long m = __ballot(s == e);
    if (lane == 0) wc[w][e] = __popcll(m);
  }
  __syncthreads();
  if (tid < NE) bc[blockIdx.x * NE + tid] = wc[0][tid] + wc[1][tid] + wc[2][tid] + wc[3][tid];
}

// deterministic scan: blockCounts -> absolute blockOffs, atom_start, tile_off
__global__ void scan_k(const int* __restrict__ bc, int* __restrict__ bo,
                       int* __restrict__ atom_start, int* __restrict__ tile_off,
                       int nblocks, int NE) {
  __shared__ int csum[256];
  __shared__ int coff[256];
  __shared__ int stot[16];
  __shared__ int sbase[16];
  int tid = threadIdx.x;
  int per = (nblocks + CHUNKS - 1) / CHUNKS;
  int e = tid / CHUNKS, c = tid % CHUNKS;
  int b0 = c * per, b1 = b0 + per; if (b1 > nblocks) b1 = nblocks;
  if (tid < NE * CHUNKS) {
    int s = 0;
    for (int b = b0; b < b1; ++b) s += bc[b * NE + e];
    csum[tid] = s;
  }
  __syncthreads();
  if (tid < NE) {
    int r = 0;
    for (int c2 = 0; c2 < CHUNKS; ++c2) { coff[tid * CHUNKS + c2] = r; r += csum[tid * CHUNKS + c2]; }
    stot[tid] = r;
  }
  __syncthreads();
  if (tid == 0) {
    int a = 0, t = 0;
    for (int e2 = 0; e2 < NE; ++e2) {
      sbase[e2] = a;
      atom_start[e2] = a; tile_off[e2] = t;
      a += stot[e2]; t += (stot[e2] + TROWS - 1) / TROWS;
    }
    atom_start[NE] = a; tile_off[NE] = t;
  }
  __syncthreads();
  if (tid < NE * CHUNKS) {
    int run = sbase[e] + coff[tid];
    for (int b = b0; b < b1; ++b) { bo[b * NE + e] = run; run += bc[b * NE + e]; }
  }
}

// deterministic scatter: rank = block-offset + wave-prefix + lane-prefix
__global__ void dscatter_k(const int* __restrict__ sp, int n, const int* __restrict__ bo,
                           int* __restrict__ sorted, int NE) {
  __shared__ int wc[4][16];
  int tid = threadIdx.x;
  int i = blockIdx.x * 256 + tid;
  int s = (i < n) ? sp[i] : -1;
  int w = tid >> 6, lane = tid & 63;
  for (int e = 0; e < NE; ++e) {
    unsigned long long m = __ballot(s == e);
    if (lane == 0) wc[w][e] = __popcll(m);
  }
  __syncthreads();
  for (int e = 0; e < NE; ++e) {
    unsigned long long m = __ballot(s == e);
    if (s == e) {
      int wpre = 0;
      for (int w2 = 0; w2 < 4; ++w2) if (w2 < w) wpre += wc[w2][e];
      int rank = __popcll(m & ((1ull << lane) - 1ull));
      sorted[bo[blockIdx.x * NE + e] + wpre + rank] = i;
    }
  }
}

// ---- fused grouped GEMM + SiLU + layer2 ------------------------------------

__global__ __launch_bounds__(256) void gemm_k(
    const float* __restrict__ x, const unsigned short* __restrict__ wt,
    const float* __restrict__ b1, const float* __restrict__ w2,
    const float* __restrict__ b2, const int* __restrict__ sorted,
    const int* __restrict__ atom_start, const int* __restrict__ tile_off,
    float* __restrict__ out, int NE)
{
  // LDS: A tile 32 rows x 1040B fp32 = 33280 B (padded pitch, 2-way banks),
  //      B single buffer 16 KB (reused as 0.5 KB partial buffer in epilogue).
  // Total 49664 B -> 3 blocks/CU.
  __shared__ __align__(16) char smem[TROWS * ROWB + BCHUNK];
  char* ldsA = smem;
  char* ldsB = smem + TROWS * ROWB;
  float* partLds = (float*)ldsB;

  int b = blockIdx.x;
  if (b >= tile_off[NE]) return;
  int e = NE - 1;
  for (int i = 0; i < NE; ++i) { if (b < tile_off[i + 1]) { e = i; break; } }
  int t = b - tile_off[e];
  int rowStart = atom_start[e] + t * TROWS;
  int rowsValid = atom_start[e + 1] - rowStart;
  if (rowsValid > TROWS) rowsValid = TROWS;

  int tid = threadIdx.x;
  int lane = tid & 63, wid = tid >> 6;

  const char* wbase = (const char*)wt + (size_t)e * 8 * BCHUNK;

  // ---- prologue: whole fp32 A tile async in flight (zero VGPR cost) ----
  #pragma unroll
  for (int i = 0; i < TROWS / 4 / 8 * 8; ++i) { }   // (kept trivial; real loop below)
  #pragma unroll
  for (int i = 0; i < 8; ++i) {
    int r = wid * 8 + i;
    int rr = (r < rowsValid) ? r : (rowsValid - 1);
    int atom = sorted[rowStart + rr];
    gload_lds16(x + (size_t)atom * NDIM + lane * 4, ldsA + r * ROWB);
  }

  int lr = lane & 15, lg = lane >> 4;

  f32x4 acc[2][4];
  const f32x4 zero = {0.f, 0.f, 0.f, 0.f};
  #pragma unroll
  for (int i = 0; i < 2; ++i)
    #pragma unroll
    for (int j = 0; j < 4; ++j) acc[i][j] = zero;

  // ---- K loop: single-buffer B, 2 barriers/step; A latency amortized by
  //      3 blocks/CU and the full-tile prologue prefetch ----
  for (int step = 0; step < 8; ++step) {
    __syncthreads();   // prev step done reading ldsB
    {
      const char* src = wbase + (size_t)step * BCHUNK;
      #pragma unroll
      for (int j = 0; j < 4; ++j)
        gload_lds16(src + wid * 4096 + j * 1024 + lane * 16,
                    ldsB + wid * 4096 + j * 1024);
    }
    __syncthreads();   // drains vmcnt: A (first iter) + this B chunk

    int k0 = step * 32;
    short8 af[2], bf[4];
    #pragma unroll
    for (int mf = 0; mf < 2; ++mf) {
      int r = mf * 16 + lr;
      const char* p = ldsA + r * ROWB + (k0 + lg * 8) * 4;
      float4 lo = *(const float4*)p;
      float4 hi = *(const float4*)(p + 16);
      af[mf] = cvt8(lo, hi);
    }
    #pragma unroll
    for (int nf = 0; nf < 4; ++nf) {
      int n = wid * 64 + nf * 16 + lr;
      unsigned off = ((unsigned)(n * 64 + lg * 16)) ^ ((unsigned)((n & 7) << 4));
      bf[nf] = *(const short8*)(ldsB + off);
    }
    #pragma unroll
    for (int mf = 0; mf < 2; ++mf)
      #pragma unroll
      for (int nf = 0; nf < 4; ++nf)
        acc[mf][nf] = __builtin_amdgcn_mfma_f32_16x16x32_bf16(af[mf], bf[nf], acc[mf][nf], 0, 0, 0);
  }

  // ---- epilogue: +b1, SiLU, dot with W2, reduce ----
  // C/D layout: col = lane&15 (+nf*16 + wid*64), row = (lane>>4)*4 + reg (+mf*16)
  const float* b1p = b1 + (size_t)e * NDIM;
  const float* w2p = w2 + (size_t)e * NDIM;
  float psum[2][4];
  #pragma unroll
  for (int mf = 0; mf < 2; ++mf)
    #pragma unroll
    for (int rg = 0; rg < 4; ++rg) psum[mf][rg] = 0.f;

  #pragma unroll
  for (int nf = 0; nf < 4; ++nf) {
    int ncol = wid * 64 + nf * 16 + lr;
    float bb = b1p[ncol];
    float wv = w2p[ncol];
    #pragma unroll
    for (int mf = 0; mf < 2; ++mf)
      #pragma unroll
      for (int rg = 0; rg < 4; ++rg) {
        float h = acc[mf][nf][rg] + bb;
        float sv = h * __builtin_amdgcn_rcpf(1.f + __expf(-h));   // SiLU
        psum[mf][rg] += sv * wv;
      }
  }

  // reduce over the 16 lanes sharing lg (sums this wave's 64 columns)
  #pragma unroll
  for (int mf = 0; mf < 2; ++mf)
    #pragma unroll
    for (int rg = 0; rg < 4; ++rg) {
      float v = psum[mf][rg];
      v += __shfl_xor(v, 1, 64);
      v += __shfl_xor(v, 2, 64);
      v += __shfl_xor(v, 4, 64);
      v += __shfl_xor(v, 8, 64);
      psum[mf][rg] = v;
    }

  __syncthreads();   // all waves past final B reads -> safe to reuse as partLds
  if (lr == 0) {
    #pragma unroll
    for (int mf = 0; mf < 2; ++mf)
      #pragma unroll
      for (int rg = 0; rg < 4; ++rg)
        partLds[wid * TROWS + mf * 16 + lg * 4 + rg] = psum[mf][rg];
  }
  __syncthreads();
  if (tid < TROWS && tid < rowsValid) {
    float s = partLds[tid] + partLds[TROWS + tid] + partLds[2 * TROWS + tid]
            + partLds[3 * TROWS + tid] + b2[e];
    out[sorted[rowStart + tid]] = s;
  }
}

// ---- launch -----------------------------------------------------------------

extern "C" void kernel_launch(void* const* d_in, const int* in_sizes, int n_in,
                              void* d_out, int out_size, void* d_ws, size_t ws_size,
                              hipStream_t stream) {
  const float* x  = (const float*)d_in[0];
  const int*   sp = (const int*)d_in[1];
  const float* W1 = (const float*)d_in[2];
  const float* b1 = (const float*)d_in[3];
  const float* W2 = (const float*)d_in[4];
  const float* b2 = (const float*)d_in[5];
  float* out = (float*)d_out;

  int n_atoms = in_sizes[0] / NDIM;
  int NE = in_sizes[2] / (NDIM * NDIM);
  int nblocks = (n_atoms + 255) / 256;

  // workspace layout (all 256-aligned); every word read is written this call.
  char* wsb = (char*)d_ws;
  size_t o = 0;
  int* bc = (int*)(wsb + o);         o += ((size_t)nblocks * NE * 4 + 255) & ~(size_t)255;
  int* bo = (int*)(wsb + o);         o += ((size_t)nblocks * NE * 4 + 255) & ~(size_t)255;
  int* atom_start = (int*)(wsb + o); o += 256;
  int* tile_off   = (int*)(wsb + o); o += 256;
  int* sorted     = (int*)(wsb + o); o += ((size_t)n_atoms * 4 + 255) & ~(size_t)255;
  unsigned short* wt = (unsigned short*)(wsb + o);   // NE*128KB, 256-aligned

  hipLaunchKernelGGL(convw_k, dim3((NE * 8192 + 255) / 256), dim3(256), 0, stream,
                     W1, wt, NE);
  hipLaunchKernelGGL(bhist_k, dim3(nblocks), dim3(256), 0, stream, sp, n_atoms, bc, NE);
  hipLaunchKernelGGL(scan_k, dim3(1), dim3(256), 0, stream, bc, bo, atom_start, tile_off,
                     nblocks, NE);
  hipLaunchKernelGGL(dscatter_k, dim3(nblocks), dim3(256), 0, stream, sp, n_atoms, bo,
                     sorted, NE);

  int maxTiles = (n_atoms + TROWS - 1) / TROWS + NE;   // extras exit on tile_off[NE]
  hipLaunchKernelGGL(gemm_k, dim3(maxTiles), dim3(256), 0, stream,
                     x, wt, b1, W2, b2, sorted, atom_start, tile_off, out, NE);
}

// Round 5
// 70.697 us; speedup vs baseline: 1.7541x; 1.0544x over previous
//
#include <hip/hip_runtime.h>
#include <hip/hip_bf16.h>
#include <stdint.h>

// ElementReadoutMLP: species-routed 2-layer MLP, fused.
// Deterministic pipeline (no atomics, no memset):
//   bhist_k / scan_k / dscatter_k : countsort atoms by species (ballot-based)
//   convw_k : W1 [e][k][n] fp32 -> wt, PRE-SWIZZLED k-chunked bf16 layout
//   gemm_k  : grouped bf16-MFMA GEMM, 32 atoms x 256 out per 512-thread block.
//             A staged fp32 via global_load_lds (full tile async, Little's law);
//             B (wave's 32-col x 256-k slice) lives in 64 VGPRs -- loaded once
//             per block, so the K-loop has ZERO barriers and zero B staging.
//             Fused bias+SiLU+W2-dot epilogue.

#define NDIM 256
#define CHUNKS 16      // scan chunks per species (NE*CHUNKS <= 256)
#define BCHUNK 16384   // bytes per B k-chunk (256 n x 32 k x 2B)
#define TROWS 32       // atoms per tile
#define ROWB 1040      // A row pitch bytes (1024+16 -> 8-lane b128 groups hit all 32 banks)

typedef __attribute__((ext_vector_type(8))) short short8;
typedef __attribute__((ext_vector_type(8))) unsigned short ushort8;
typedef __attribute__((ext_vector_type(4))) float f32x4;

__device__ __forceinline__ unsigned short f2bf(float f) {
  unsigned u = __float_as_uint(f);
  u = (u + 0x7FFFu + ((u >> 16) & 1u)) >> 16;   // round-to-nearest-even
  return (unsigned short)u;
}

// async global->LDS, 16B per lane; lds dest must be wave-uniform base.
__device__ __forceinline__ void gload_lds16(const void* gsrc, void* ldst) {
  __builtin_amdgcn_global_load_lds(
      (const __attribute__((address_space(1))) unsigned*)gsrc,
      (__attribute__((address_space(3))) unsigned*)(uintptr_t)(unsigned)(uintptr_t)ldst,
      16, 0, 0);
}

// pack 8 fp32 -> short8 of bf16 (RNE, packed cvt)
__device__ __forceinline__ short8 cvt8(float4 lo, float4 hi) {
  union { short8 s; unsigned u[4]; } r;
  __hip_bfloat162 t;
  t = __float22bfloat162_rn(make_float2(lo.x, lo.y)); r.u[0] = *(unsigned*)&t;
  t = __float22bfloat162_rn(make_float2(lo.z, lo.w)); r.u[1] = *(unsigned*)&t;
  t = __float22bfloat162_rn(make_float2(hi.x, hi.y)); r.u[2] = *(unsigned*)&t;
  t = __float22bfloat162_rn(make_float2(hi.z, hi.w)); r.u[3] = *(unsigned*)&t;
  return r.s;
}

// ---- prep kernels -----------------------------------------------------------

// wt layout: chunk(e,step) = wt + (e*8+step)*BCHUNK bytes; within chunk,
// bf16 for (n,kk) at byte ((n*64 + kk*2) ^ ((n&7)<<4)).
__global__ void convw_k(const float* __restrict__ W1, unsigned short* __restrict__ wt, int NE) {
  int t = blockIdx.x * 256 + threadIdx.x;          // ((e*8+step)*4 + g)*256 + n
  if (t >= NE * 8192) return;
  int n = t & 255;
  int g = (t >> 8) & 3;            // kk-group of 8
  int step = (t >> 10) & 7;
  int e = t >> 13;
  int k0 = step * 32 + g * 8;
  const float* src = W1 + ((size_t)e << 16) + (size_t)k0 * NDIM + n;  // stride NDIM over j
  unsigned short v[8];
  #pragma unroll
  for (int j = 0; j < 8; ++j) v[j] = f2bf(src[j * NDIM]);
  char* chunk = (char*)wt + (size_t)(e * 8 + step) * BCHUNK;
  unsigned off = ((unsigned)(n * 64 + g * 16)) ^ ((unsigned)((n & 7) << 4));
  *(ushort8*)(chunk + off) = *(ushort8*)v;
}

// per-block histogram, deterministic (ballot-based, no atomics)
__global__ void bhist_k(const int* __restrict__ sp, int n, int* __restrict__ bc, int NE) {
  __shared__ int wc[4][16];
  int tid = threadIdx.x;
  int i = blockIdx.x * 256 + tid;
  int s = (i < n) ? sp[i] : -1;
  int w = tid >> 6, lane = tid & 63;
  for (int e = 0; e < NE; ++e) {
    unsigned long long m = __ballot(s == e);
    if (lane == 0) wc[w][e] = __popcll(m);
  }
  __syncthreads();
  if (tid < NE) bc[blockIdx.x * NE + tid] = wc[0][tid] + wc[1][tid] + wc[2][tid] + wc[3][tid];
}

// deterministic scan: blockCounts -> absolute blockOffs, atom_start, tile_off
__global__ void scan_k(const int* __restrict__ bc, int* __restrict__ bo,
                       int* __restrict__ atom_start, int* __restrict__ tile_off,
                       int nblocks, int NE) {
  __shared__ int csum[256];
  __shared__ int coff[256];
  __shared__ int stot[16];
  __shared__ int sbase[16];
  int tid = threadIdx.x;
  int per = (nblocks + CHUNKS - 1) / CHUNKS;
  int e = tid / CHUNKS, c = tid % CHUNKS;
  int b0 = c * per, b1 = b0 + per; if (b1 > nblocks) b1 = nblocks;
  if (tid < NE * CHUNKS) {
    int s = 0;
    for (int b = b0; b < b1; ++b) s += bc[b * NE + e];
    csum[tid] = s;
  }
  __syncthreads();
  if (tid < NE) {
    int r = 0;
    for (int c2 = 0; c2 < CHUNKS; ++c2) { coff[tid * CHUNKS + c2] = r; r += csum[tid * CHUNKS + c2]; }
    stot[tid] = r;
  }
  __syncthreads();
  if (tid == 0) {
    int a = 0, t = 0;
    for (int e2 = 0; e2 < NE; ++e2) {
      sbase[e2] = a;
      atom_start[e2] = a; tile_off[e2] = t;
      a += stot[e2]; t += (stot[e2] + TROWS - 1) / TROWS;
    }
    atom_start[NE] = a; tile_off[NE] = t;
  }
  __syncthreads();
  if (tid < NE * CHUNKS) {
    int run = sbase[e] + coff[tid];
    for (int b = b0; b < b1; ++b) { bo[b * NE + e] = run; run += bc[b * NE + e]; }
  }
}

// deterministic scatter: rank = block-offset + wave-prefix + lane-prefix
__global__ void dscatter_k(const int* __restrict__ sp, int n, const int* __restrict__ bo,
                           int* __restrict__ sorted, int NE) {
  __shared__ int wc[4][16];
  int tid = threadIdx.x;
  int i = blockIdx.x * 256 + tid;
  int s = (i < n) ? sp[i] : -1;
  int w = tid >> 6, lane = tid & 63;
  for (int e = 0; e < NE; ++e) {
    unsigned long long m = __ballot(s == e);
    if (lane == 0) wc[w][e] = __popcll(m);
  }
  __syncthreads();
  for (int e = 0; e < NE; ++e) {
    unsigned long long m = __ballot(s == e);
    if (s == e) {
      int wpre = 0;
      for (int w2 = 0; w2 < 4; ++w2) if (w2 < w) wpre += wc[w2][e];
      int rank = __popcll(m & ((1ull << lane) - 1ull));
      sorted[bo[blockIdx.x * NE + e] + wpre + rank] = i;
    }
  }
}

// ---- fused grouped GEMM + SiLU + layer2 ------------------------------------

__global__ __launch_bounds__(512, 4) void gemm_k(
    const float* __restrict__ x, const unsigned short* __restrict__ wt,
    const float* __restrict__ b1, const float* __restrict__ w2,
    const float* __restrict__ b2, const int* __restrict__ sorted,
    const int* __restrict__ atom_start, const int* __restrict__ tile_off,
    float* __restrict__ out, int NE)
{
  // LDS: A tile 32 rows x 1040B fp32 = 33280 B + 1 KB cross-wave partials.
  // ~34.3 KB -> 2 blocks/CU (wave-limited at 16 waves/CU with VGPR<=128).
  __shared__ __align__(16) char smem[TROWS * ROWB + 1024];
  char* ldsA = smem;
  float* partLds = (float*)(smem + TROWS * ROWB);

  int b = blockIdx.x;
  if (b >= tile_off[NE]) return;
  int e = NE - 1;
  for (int i = 0; i < NE; ++i) { if (b < tile_off[i + 1]) { e = i; break; } }
  int t = b - tile_off[e];
  int rowStart = atom_start[e] + t * TROWS;
  int rowsValid = atom_start[e + 1] - rowStart;
  if (rowsValid > TROWS) rowsValid = TROWS;

  int tid = threadIdx.x;
  int lane = tid & 63, wid = tid >> 6;   // wid 0..7
  int lr = lane & 15, lg = lane >> 4;

  // ---- issue whole fp32 A tile async (4 rows per wave, zero VGPR cost) ----
  #pragma unroll
  for (int i = 0; i < 4; ++i) {
    int r = wid * 4 + i;
    int rr = (r < rowsValid) ? r : (rowsValid - 1);
    int atom = sorted[rowStart + rr];
    gload_lds16(x + (size_t)atom * NDIM + lane * 4, ldsA + r * ROWB);
  }

  // ---- B slice into registers: wave owns n-cols [wid*32, wid*32+32) ----
  // bf[nf][step] is the exact MFMA B-fragment; 16 x 16B coalesced loads/lane.
  const char* wbase = (const char*)wt + (size_t)e * 8 * BCHUNK;
  short8 bf[2][8];
  #pragma unroll
  for (int nf = 0; nf < 2; ++nf) {
    int n = wid * 32 + nf * 16 + lr;
    unsigned off = ((unsigned)(n * 64 + lg * 16)) ^ ((unsigned)((n & 7) << 4));
    #pragma unroll
    for (int s = 0; s < 8; ++s)
      bf[nf][s] = *(const short8*)(wbase + (size_t)s * BCHUNK + off);
  }

  f32x4 acc[2][2];
  const f32x4 zero = {0.f, 0.f, 0.f, 0.f};
  #pragma unroll
  for (int i = 0; i < 2; ++i)
    #pragma unroll
    for (int j = 0; j < 2; ++j) acc[i][j] = zero;

  __syncthreads();   // drains A DMA (vmcnt); B regs waited on by first use

  // ---- K loop: ZERO barriers, pure ds_read + cvt + MFMA ----
  #pragma unroll
  for (int step = 0; step < 8; ++step) {
    int k0 = step * 32;
    short8 af[2];
    #pragma unroll
    for (int mf = 0; mf < 2; ++mf) {
      int r = mf * 16 + lr;
      const char* p = ldsA + r * ROWB + (k0 + lg * 8) * 4;
      float4 lo = *(const float4*)p;
      float4 hi = *(const float4*)(p + 16);
      af[mf] = cvt8(lo, hi);
    }
    #pragma unroll
    for (int mf = 0; mf < 2; ++mf)
      #pragma unroll
      for (int nf = 0; nf < 2; ++nf)
        acc[mf][nf] = __builtin_amdgcn_mfma_f32_16x16x32_bf16(af[mf], bf[nf][step], acc[mf][nf], 0, 0, 0);
  }

  // ---- epilogue: +b1, SiLU, dot with W2, reduce ----
  // C/D layout: col = lane&15 (+nf*16 + wid*32), row = (lane>>4)*4 + reg (+mf*16)
  const float* b1p = b1 + (size_t)e * NDIM;
  const float* w2p = w2 + (size_t)e * NDIM;
  float psum[2][4];
  #pragma unroll
  for (int mf = 0; mf < 2; ++mf)
    #pragma unroll
    for (int rg = 0; rg < 4; ++rg) psum[mf][rg] = 0.f;

  #pragma unroll
  for (int nf = 0; nf < 2; ++nf) {
    int ncol = wid * 32 + nf * 16 + lr;
    float bb = b1p[ncol];
    float wv = w2p[ncol];
    #pragma unroll
    for (int mf = 0; mf < 2; ++mf)
      #pragma unroll
      for (int rg = 0; rg < 4; ++rg) {
        float h = acc[mf][nf][rg] + bb;
        float sv = h * __builtin_amdgcn_rcpf(1.f + __expf(-h));   // SiLU
        psum[mf][rg] += sv * wv;
      }
  }

  // reduce over the 16 lanes sharing lg (sums this wave's 32 columns)
  #pragma unroll
  for (int mf = 0; mf < 2; ++mf)
    #pragma unroll
    for (int rg = 0; rg < 4; ++rg) {
      float v = psum[mf][rg];
      v += __shfl_xor(v, 1, 64);
      v += __shfl_xor(v, 2, 64);
      v += __shfl_xor(v, 4, 64);
      v += __shfl_xor(v, 8, 64);
      psum[mf][rg] = v;
    }

  // cross-wave: partLds[w][row], 8 x 32 floats
  if (lr == 0) {
    #pragma unroll
    for (int mf = 0; mf < 2; ++mf)
      #pragma unroll
      for (int rg = 0; rg < 4; ++rg)
        partLds[wid * TROWS + mf * 16 + lg * 4 + rg] = psum[mf][rg];
  }
  __syncthreads();
  if (tid < TROWS && tid < rowsValid) {
    float s = b2[e];
    #pragma unroll
    for (int w = 0; w < 8; ++w) s += partLds[w * TROWS + tid];
    out[sorted[rowStart + tid]] = s;
  }
}

// ---- launch -----------------------------------------------------------------

extern "C" void kernel_launch(void* const* d_in, const int* in_sizes, int n_in,
                              void* d_out, int out_size, void* d_ws, size_t ws_size,
                              hipStream_t stream) {
  const float* x  = (const float*)d_in[0];
  const int*   sp = (const int*)d_in[1];
  const float* W1 = (const float*)d_in[2];
  const float* b1 = (const float*)d_in[3];
  const float* W2 = (const float*)d_in[4];
  const float* b2 = (const float*)d_in[5];
  float* out = (float*)d_out;

  int n_atoms = in_sizes[0] / NDIM;
  int NE = in_sizes[2] / (NDIM * NDIM);
  int nblocks = (n_atoms + 255) / 256;

  // workspace layout (all 256-aligned); every word read is written this call.
  char* wsb = (char*)d_ws;
  size_t o = 0;
  int* bc = (int*)(wsb + o);         o += ((size_t)nblocks * NE * 4 + 255) & ~(size_t)255;
  int* bo = (int*)(wsb + o);         o += ((size_t)nblocks * NE * 4 + 255) & ~(size_t)255;
  int* atom_start = (int*)(wsb + o); o += 256;
  int* tile_off   = (int*)(wsb + o); o += 256;
  int* sorted     = (int*)(wsb + o); o += ((size_t)n_atoms * 4 + 255) & ~(size_t)255;
  unsigned short* wt = (unsigned short*)(wsb + o);   // NE*128KB, 256-aligned

  hipLaunchKernelGGL(convw_k, dim3((NE * 8192 + 255) / 256), dim3(256), 0, stream,
                     W1, wt, NE);
  hipLaunchKernelGGL(bhist_k, dim3(nblocks), dim3(256), 0, stream, sp, n_atoms, bc, NE);
  hipLaunchKernelGGL(scan_k, dim3(1), dim3(256), 0, stream, bc, bo, atom_start, tile_off,
                     nblocks, NE);
  hipLaunchKernelGGL(dscatter_k, dim3(nblocks), dim3(256), 0, stream, sp, n_atoms, bo,
                     sorted, NE);

  int maxTiles = (n_atoms + TROWS - 1) / TROWS + NE;   // extras exit on tile_off[NE]
  hipLaunchKernelGGL(gemm_k, dim3(maxTiles), dim3(512), 0, stream,
                     x, wt, b1, W2, b2, sorted, atom_start, tile_off, out, NE);
}

// Round 6
// 69.831 us; speedup vs baseline: 1.7758x; 1.0124x over previous
//
#include <hip/hip_runtime.h>
#include <hip/hip_bf16.h>
#include <stdint.h>

// ElementReadoutMLP: species-routed 2-layer MLP, fused.
// Deterministic pipeline (no atomics, no memset):
//   bhist_k / scan_k / dscatter_k : countsort atoms by species (ballot-based)
//   convw_k : W1 [e][k][n] fp32 -> wt, PRE-SWIZZLED k-chunked bf16 layout
//   gemm_k  : PERSISTENT grouped GEMM. 512 blocks; each block owns ~6
//             contiguous 32-atom tiles (species-sorted). The wave's B slice
//             (32 cols x 256 k = 64 VGPRs) is loaded ONCE per species change
//             and lives across the tile loop -- B traffic drops 400MB -> 67MB.
//             A double-buffered via global_load_lds with stage-ahead; the
//             mid-tile barrier skips the vmcnt drain (T4) so the next tile's
//             DMA stays in flight. Fused bias+SiLU+W2-dot epilogue.

#define NDIM 256
#define CHUNKS 16      // scan chunks per species (NE*CHUNKS <= 256)
#define BCHUNK 16384   // bytes per B k-chunk (256 n x 32 k x 2B)
#define TROWS 32       // atoms per tile
#define ROWB 1040      // A row pitch bytes (65*16 -> odd 16B-granule stride)

typedef __attribute__((ext_vector_type(8))) short short8;
typedef __attribute__((ext_vector_type(8))) unsigned short ushort8;
typedef __attribute__((ext_vector_type(4))) float f32x4;

__device__ __forceinline__ unsigned short f2bf(float f) {
  unsigned u = __float_as_uint(f);
  u = (u + 0x7FFFu + ((u >> 16) & 1u)) >> 16;   // round-to-nearest-even
  return (unsigned short)u;
}

// async global->LDS, 16B per lane; lds dest must be wave-uniform base.
__device__ __forceinline__ void gload_lds16(const void* gsrc, void* ldst) {
  __builtin_amdgcn_global_load_lds(
      (const __attribute__((address_space(1))) unsigned*)gsrc,
      (__attribute__((address_space(3))) unsigned*)(uintptr_t)(unsigned)(uintptr_t)ldst,
      16, 0, 0);
}

// pack 8 fp32 -> short8 of bf16 (RNE, packed cvt)
__device__ __forceinline__ short8 cvt8(float4 lo, float4 hi) {
  union { short8 s; unsigned u[4]; } r;
  __hip_bfloat162 t;
  t = __float22bfloat162_rn(make_float2(lo.x, lo.y)); r.u[0] = *(unsigned*)&t;
  t = __float22bfloat162_rn(make_float2(lo.z, lo.w)); r.u[1] = *(unsigned*)&t;
  t = __float22bfloat162_rn(make_float2(hi.x, hi.y)); r.u[2] = *(unsigned*)&t;
  t = __float22bfloat162_rn(make_float2(hi.z, hi.w)); r.u[3] = *(unsigned*)&t;
  return r.s;
}

// ---- prep kernels -----------------------------------------------------------

// wt layout: chunk(e,step) = wt + (e*8+step)*BCHUNK bytes; within chunk,
// bf16 for (n,kk) at byte ((n*64 + kk*2) ^ ((n&7)<<4)).
__global__ void convw_k(const float* __restrict__ W1, unsigned short* __restrict__ wt, int NE) {
  int t = blockIdx.x * 256 + threadIdx.x;          // ((e*8+step)*4 + g)*256 + n
  if (t >= NE * 8192) return;
  int n = t & 255;
  int g = (t >> 8) & 3;            // kk-group of 8
  int step = (t >> 10) & 7;
  int e = t >> 13;
  int k0 = step * 32 + g * 8;
  const float* src = W1 + ((size_t)e << 16) + (size_t)k0 * NDIM + n;  // stride NDIM over j
  unsigned short v[8];
  #pragma unroll
  for (int j = 0; j < 8; ++j) v[j] = f2bf(src[j * NDIM]);
  char* chunk = (char*)wt + (size_t)(e * 8 + step) * BCHUNK;
  unsigned off = ((unsigned)(n * 64 + g * 16)) ^ ((unsigned)((n & 7) << 4));
  *(ushort8*)(chunk + off) = *(ushort8*)v;
}

// per-block histogram, deterministic (ballot-based, no atomics)
__global__ void bhist_k(const int* __restrict__ sp, int n, int* __restrict__ bc, int NE) {
  __shared__ int wc[4][16];
  int tid = threadIdx.x;
  int i = blockIdx.x * 256 + tid;
  int s = (i < n) ? sp[i] : -1;
  int w = tid >> 6, lane = tid & 63;
  for (int e = 0; e < NE; ++e) {
    unsigned long long m = __ballot(s == e);
    if (lane == 0) wc[w][e] = __popcll(m);
  }
  __syncthreads();
  if (tid < NE) bc[blockIdx.x * NE + tid] = wc[0][tid] + wc[1][tid] + wc[2][tid] + wc[3][tid];
}

// deterministic scan: blockCounts -> absolute blockOffs, atom_start, tile_off
__global__ void scan_k(const int* __restrict__ bc, int* __restrict__ bo,
                       int* __restrict__ atom_start, int* __restrict__ tile_off,
                       int nblocks, int NE) {
  __shared__ int csum[256];
  __shared__ int coff[256];
  __shared__ int stot[16];
  __shared__ int sbase[16];
  int tid = threadIdx.x;
  int per = (nblocks + CHUNKS - 1) / CHUNKS;
  int e = tid / CHUNKS, c = tid % CHUNKS;
  int b0 = c * per, b1 = b0 + per; if (b1 > nblocks) b1 = nblocks;
  if (tid < NE * CHUNKS) {
    int s = 0;
    for (int b = b0; b < b1; ++b) s += bc[b * NE + e];
    csum[tid] = s;
  }
  __syncthreads();
  if (tid < NE) {
    int r = 0;
    for (int c2 = 0; c2 < CHUNKS; ++c2) { coff[tid * CHUNKS + c2] = r; r += csum[tid * CHUNKS + c2]; }
    stot[tid] = r;
  }
  __syncthreads();
  if (tid == 0) {
    int a = 0, t = 0;
    for (int e2 = 0; e2 < NE; ++e2) {
      sbase[e2] = a;
      atom_start[e2] = a; tile_off[e2] = t;
      a += stot[e2]; t += (stot[e2] + TROWS - 1) / TROWS;
    }
    atom_start[NE] = a; tile_off[NE] = t;
  }
  __syncthreads();
  if (tid < NE * CHUNKS) {
    int run = sbase[e] + coff[tid];
    for (int b = b0; b < b1; ++b) { bo[b * NE + e] = run; run += bc[b * NE + e]; }
  }
}

// deterministic scatter: rank = block-offset + wave-prefix + lane-prefix
__global__ void dscatter_k(const int* __restrict__ sp, int n, const int* __restrict__ bo,
                           int* __restrict__ sorted, int NE) {
  __shared__ int wc[4][16];
  int tid = threadIdx.x;
  int i = blockIdx.x * 256 + tid;
  int s = (i < n) ? sp[i] : -1;
  int w = tid >> 6, lane = tid & 63;
  for (int e = 0; e < NE; ++e) {
    unsigned long long m = __ballot(s == e);
    if (lane == 0) wc[w][e] = __popcll(m);
  }
  __syncthreads();
  for (int e = 0; e < NE; ++e) {
    unsigned long long m = __ballot(s == e);
    if (s == e) {
      int wpre = 0;
      for (int w2 = 0; w2 < 4; ++w2) if (w2 < w) wpre += wc[w2][e];
      int rank = __popcll(m & ((1ull << lane) - 1ull));
      sorted[bo[blockIdx.x * NE + e] + wpre + rank] = i;
    }
  }
}

// ---- persistent fused grouped GEMM + SiLU + layer2 --------------------------

__global__ __launch_bounds__(512, 4) void gemm_k(
    const float* __restrict__ x, const unsigned short* __restrict__ wt,
    const float* __restrict__ b1, const float* __restrict__ w2,
    const float* __restrict__ b2, const int* __restrict__ sorted,
    const int* __restrict__ atom_start, const int* __restrict__ tile_off,
    float* __restrict__ out, int NE)
{
  // LDS: A double buffer 2 x 32 x 1040B fp32 = 66560 B + partials + tables.
  __shared__ __align__(16) char ldsA[2][TROWS * ROWB];
  __shared__ float partLds[256];        // 8 waves x 32 rows
  __shared__ int toffs[17], astart[17];

  int tid = threadIdx.x, lane = tid & 63, wid = tid >> 6;   // wid 0..7
  int lr = lane & 15, lg = lane >> 4;

  if (tid <= NE) { toffs[tid] = tile_off[tid]; astart[tid] = atom_start[tid]; }
  __syncthreads();

  int ntiles = toffs[NE];
  int nb = gridDim.x, b = blockIdx.x;
  int q = ntiles / nb, rem = ntiles % nb;
  int t0 = b * q + (b < rem ? b : rem);
  int cnt = q + (b < rem ? 1 : 0);
  if (cnt <= 0) return;
  int t1 = t0 + cnt;

  int held_e = -1;
  short8 bf[2][8];          // wave's B slice: 32 cols x 256 k (64 VGPRs, live)
  float bbv[2], wvv[2], b2v = 0.f;

  auto stageA = [&](int t, int buf) {
    int e = 0;
    while (t >= toffs[e + 1]) ++e;
    int rs = astart[e] + (t - toffs[e]) * TROWS;
    int rv = astart[e + 1] - rs; if (rv > TROWS) rv = TROWS;
    #pragma unroll
    for (int i = 0; i < 4; ++i) {
      int rrow = wid * 4 + i;
      int rcl = (rrow < rv) ? rrow : (rv - 1);
      int atom = sorted[rs + rcl];
      gload_lds16(x + (size_t)atom * NDIM + lane * 4, &ldsA[buf][rrow * ROWB]);
    }
  };

  stageA(t0, 0);

  for (int t = t0; t < t1; ++t) {
    int buf = (t - t0) & 1;
    int e = 0;
    while (t >= toffs[e + 1]) ++e;
    int rs = astart[e] + (t - toffs[e]) * TROWS;
    int rv = astart[e + 1] - rs; if (rv > TROWS) rv = TROWS;

    if (e != held_e) {        // ~once per block: load B slice + layer params
      held_e = e;
      const char* wbase = (const char*)wt + (size_t)e * 8 * BCHUNK;
      #pragma unroll
      for (int nf = 0; nf < 2; ++nf) {
        int ncol = wid * 32 + nf * 16 + lr;
        unsigned off = ((unsigned)(ncol * 64 + lg * 16)) ^ ((unsigned)((ncol & 7) << 4));
        #pragma unroll
        for (int s = 0; s < 8; ++s)
          bf[nf][s] = *(const short8*)(wbase + (size_t)s * BCHUNK + off);
        bbv[nf] = b1[(size_t)e * NDIM + ncol];
        wvv[nf] = w2[(size_t)e * NDIM + ncol];
      }
      b2v = b2[e];
    }

    // barrier1: full __syncthreads -- drains A(t) DMA (issued a whole tile
    // ago, fully hidden) and closes prev tile's partLds reads.
    __syncthreads();
    if (t + 1 < t1) stageA(t + 1, buf ^ 1);   // in flight across barrier2

    // ---- compute: 8 K-steps, no barriers ----
    f32x4 acc[2][2];
    const f32x4 zero = {0.f, 0.f, 0.f, 0.f};
    #pragma unroll
    for (int i = 0; i < 2; ++i)
      #pragma unroll
      for (int j = 0; j < 2; ++j) acc[i][j] = zero;

    const char* Ab = ldsA[buf];
    #pragma unroll
    for (int step = 0; step < 8; ++step) {
      int k0 = step * 32;
      short8 af[2];
      #pragma unroll
      for (int mf = 0; mf < 2; ++mf) {
        const char* p = Ab + (mf * 16 + lr) * ROWB + (k0 + lg * 8) * 4;
        float4 lo = *(const float4*)p;
        float4 hi = *(const float4*)(p + 16);
        af[mf] = cvt8(lo, hi);
      }
      #pragma unroll
      for (int mf = 0; mf < 2; ++mf)
        #pragma unroll
        for (int nf = 0; nf < 2; ++nf)
          acc[mf][nf] = __builtin_amdgcn_mfma_f32_16x16x32_bf16(af[mf], bf[nf][step], acc[mf][nf], 0, 0, 0);
    }

    // ---- epilogue: +b1, SiLU, dot W2, reduce ----
    float psum[2][4];
    #pragma unroll
    for (int mf = 0; mf < 2; ++mf)
      #pragma unroll
      for (int rg = 0; rg < 4; ++rg) psum[mf][rg] = 0.f;

    #pragma unroll
    for (int nf = 0; nf < 2; ++nf) {
      #pragma unroll
      for (int mf = 0; mf < 2; ++mf)
        #pragma unroll
        for (int rg = 0; rg < 4; ++rg) {
          float h = acc[mf][nf][rg] + bbv[nf];
          float sv = h * __builtin_amdgcn_rcpf(1.f + __expf(-h));   // SiLU
          psum[mf][rg] += sv * wvv[nf];
        }
    }
    #pragma unroll
    for (int mf = 0; mf < 2; ++mf)
      #pragma unroll
      for (int rg = 0; rg < 4; ++rg) {
        float v = psum[mf][rg];
        v += __shfl_xor(v, 1, 64);
        v += __shfl_xor(v, 2, 64);
        v += __shfl_xor(v, 4, 64);
        v += __shfl_xor(v, 8, 64);
        psum[mf][rg] = v;
      }
    if (lr == 0) {
      #pragma unroll
      for (int mf = 0; mf < 2; ++mf)
        #pragma unroll
        for (int rg = 0; rg < 4; ++rg)
          partLds[wid * TROWS + mf * 16 + lg * 4 + rg] = psum[mf][rg];
    }

    // barrier2: LDS-only barrier -- does NOT drain vmcnt, so A(t+1)'s DMA
    // stays in flight (T4). partials ordered by lgkmcnt.
    asm volatile("s_waitcnt lgkmcnt(0)\n\ts_barrier" ::: "memory");

    if (tid < TROWS && tid < rv) {
      float s = b2v;
      #pragma unroll
      for (int w = 0; w < 8; ++w) s += partLds[w * TROWS + tid];
      out[sorted[rs + tid]] = s;
    }
  }
}

// ---- launch -----------------------------------------------------------------

extern "C" void kernel_launch(void* const* d_in, const int* in_sizes, int n_in,
                              void* d_out, int out_size, void* d_ws, size_t ws_size,
                              hipStream_t stream) {
  const float* x  = (const float*)d_in[0];
  const int*   sp = (const int*)d_in[1];
  const float* W1 = (const float*)d_in[2];
  const float* b1 = (const float*)d_in[3];
  const float* W2 = (const float*)d_in[4];
  const float* b2 = (const float*)d_in[5];
  float* out = (float*)d_out;

  int n_atoms = in_sizes[0] / NDIM;
  int NE = in_sizes[2] / (NDIM * NDIM);
  int nblocks = (n_atoms + 255) / 256;

  // workspace layout (all 256-aligned); every word read is written this call.
  char* wsb = (char*)d_ws;
  size_t o = 0;
  int* bc = (int*)(wsb + o);         o += ((size_t)nblocks * NE * 4 + 255) & ~(size_t)255;
  int* bo = (int*)(wsb + o);         o += ((size_t)nblocks * NE * 4 + 255) & ~(size_t)255;
  int* atom_start = (int*)(wsb + o); o += 256;
  int* tile_off   = (int*)(wsb + o); o += 256;
  int* sorted     = (int*)(wsb + o); o += ((size_t)n_atoms * 4 + 255) & ~(size_t)255;
  unsigned short* wt = (unsigned short*)(wsb + o);   // NE*128KB, 256-aligned

  hipLaunchKernelGGL(convw_k, dim3((NE * 8192 + 255) / 256), dim3(256), 0, stream,
                     W1, wt, NE);
  hipLaunchKernelGGL(bhist_k, dim3(nblocks), dim3(256), 0, stream, sp, n_atoms, bc, NE);
  hipLaunchKernelGGL(scan_k, dim3(1), dim3(256), 0, stream, bc, bo, atom_start, tile_off,
                     nblocks, NE);
  hipLaunchKernelGGL(dscatter_k, dim3(nblocks), dim3(256), 0, stream, sp, n_atoms, bo,
                     sorted, NE);

  hipLaunchKernelGGL(gemm_k, dim3(512), dim3(512), 0, stream,
                     x, wt, b1, W2, b2, sorted, atom_start, tile_off, out, NE);
}